// Round 1
// 2231.364 us; speedup vs baseline: 1.1294x; 1.1294x over previous
//
#include <hip/hip_runtime.h>
#include <stdint.h>

#define N_TOK 8192
#define DMODEL 2048
#define VOCAB 50257
#define VPAD 50432            // 197 * 256
#define IGNORE_INDEX (-100)

#define BM 256
#define BN 256
#define BK 64
#define NKT (DMODEL / BK)     // 32 k-tiles
#define N_RT (N_TOK / BM)     // 32 row tiles
#define N_VT (VPAD / BN)      // 197 vocab tiles

typedef __attribute__((ext_vector_type(8))) short short8;
typedef __attribute__((ext_vector_type(4))) float float4v;

__device__ __forceinline__ unsigned short f32_to_bf16(float f) {
  union { float f; uint32_t u; } v; v.f = f;
  uint32_t u = v.u;
  uint32_t r = u + 0x7fffu + ((u >> 16) & 1u);   // round-to-nearest-even
  return (unsigned short)(r >> 16);
}

__device__ __forceinline__ void gl2lds16(const unsigned short* g, unsigned short* l) {
  __builtin_amdgcn_global_load_lds(
      (const __attribute__((address_space(1))) void*)g,
      (__attribute__((address_space(3))) void*)l,
      16, 0, 0);
}

// ---- conversion kernels -------------------------------------------------

__global__ void convert_c_kernel(const float* __restrict__ c,
                                 unsigned short* __restrict__ cbf) {
  size_t idx4 = (size_t)blockIdx.x * 256 + threadIdx.x;   // 4 elems per thread
  size_t base = idx4 * 4;
  ushort4 o;
  if (base < (size_t)VOCAB * DMODEL) {
    const float4* c4 = (const float4*)c;
    float4 f = c4[idx4];
    o.x = f32_to_bf16(f.x); o.y = f32_to_bf16(f.y);
    o.z = f32_to_bf16(f.z); o.w = f32_to_bf16(f.w);
  } else {
    o.x = 0; o.y = 0; o.z = 0; o.w = 0;                   // pad rows -> 0
  }
  ((ushort4*)cbf)[idx4] = o;
}

__global__ void convert_e_kernel(const float* __restrict__ e,
                                 unsigned short* __restrict__ ebf) {
  size_t idx4 = (size_t)blockIdx.x * 256 + threadIdx.x;
  const float4* e4 = (const float4*)e;
  float4 f = e4[idx4];
  ushort4 o;
  o.x = f32_to_bf16(f.x); o.y = f32_to_bf16(f.y);
  o.z = f32_to_bf16(f.z); o.w = f32_to_bf16(f.w);
  ((ushort4*)ebf)[idx4] = o;
}

__global__ void init_kernel(float* __restrict__ p) {   // zero S and TGT
  int idx = blockIdx.x * 256 + threadIdx.x;
  if (idx < 2 * N_TOK) p[idx] = 0.0f;
}

// ---- fused 256x256 8-phase GEMM + online exp-sum ------------------------
//
// LDS map (bytes): buf d in {0,1} at d*65536:
//   +0      A half0 (block rows   0..127) 16 KB
//   +16384  A half1 (block rows 128..255) 16 KB
//   +32768  B half0 (block cols   0..127) 16 KB
//   +49152  B half1 (block cols 128..255) 16 KB
// Half layout: 128 rows x 64 bf16 (128 B/row), 16B chunk c holds global
// k-chunk c ^ (row&7)  (XOR swizzle; inverse applied on the global source,
// LDS destination stays linear for global_load_lds).
//
// Wave (wm=wid>>2, wn=wid&3): output rows {qm*128 + wm*64 .. +63},
// cols {qn*128 + wn*32 .. +31}; quadrant qm reads A half qm, qn reads B half qn.
// Phase order per K-tile: (0,0) (0,1) (1,1) (1,0)  -> LDS death times:
//   A0 dead after P0, B0 after P0 (regs kept), B1 after P1, A1 after P2.
// Stage slots tile t: P0:B0(t+1)  P1:B1(t+1)  P2:A0(t+2)  P3:A1(t+2)
// vmcnt(6) at end of P0 and P3 only (2 half-tile loads per stage, 3 in flight).

#define BARRIER() do { asm volatile("" ::: "memory"); \
                       __builtin_amdgcn_s_barrier(); \
                       asm volatile("" ::: "memory"); } while (0)
#define LGKM0()   do { asm volatile("s_waitcnt lgkmcnt(0)" ::: "memory"); \
                       __builtin_amdgcn_sched_barrier(0); } while (0)
#define VMCNT(N)  asm volatile("s_waitcnt vmcnt(" #N ")" ::: "memory")

#define stageA(H, KT2, BUF) do { \
    gl2lds16(gA##H##0 + (size_t)(KT2) * BK, \
             (unsigned short*)((BUF) + (H)*16384 + wid*2048)); \
    gl2lds16(gA##H##1 + (size_t)(KT2) * BK, \
             (unsigned short*)((BUF) + (H)*16384 + wid*2048 + 1024)); \
  } while (0)

#define stageB(H, KT2, BUF) do { \
    gl2lds16(gB##H##0 + (size_t)(KT2) * BK, \
             (unsigned short*)((BUF) + 32768 + (H)*16384 + wid*2048)); \
    gl2lds16(gB##H##1 + (size_t)(KT2) * BK, \
             (unsigned short*)((BUF) + 32768 + (H)*16384 + wid*2048 + 1024)); \
  } while (0)

#define DSA(QM) do { \
    _Pragma("unroll") \
    for (int i = 0; i < 4; ++i) { \
      a[i][0] = *(const short8*)(sd + (QM)*16384 + aoff + i*2048 + cks0); \
      a[i][1] = *(const short8*)(sd + (QM)*16384 + aoff + i*2048 + cks1); \
    } } while (0)

#define DSB(QN) do { \
    _Pragma("unroll") \
    for (int j = 0; j < 2; ++j) { \
      b##QN[j][0] = *(const short8*)(sd + 32768 + (QN)*16384 + boff + j*2048 + cks0); \
      b##QN[j][1] = *(const short8*)(sd + 32768 + (QN)*16384 + boff + j*2048 + cks1); \
    } } while (0)

#define PHASE_MFMA(QM, QN) do { \
    _Pragma("unroll") \
    for (int i = 0; i < 4; ++i) { \
      _Pragma("unroll") \
      for (int j = 0; j < 2; ++j) { \
        acc##QM##QN[i][j] = __builtin_amdgcn_mfma_f32_16x16x32_bf16( \
            a[i][0], b##QN[j][0], acc##QM##QN[i][j], 0, 0, 0); \
        acc##QM##QN[i][j] = __builtin_amdgcn_mfma_f32_16x16x32_bf16( \
            a[i][1], b##QN[j][1], acc##QM##QN[i][j], 0, 0, 0); \
      } } } while (0)

#define KTILE(KT, STB, STA, VMC_P0, VMC_P3) do { \
    const int _kt = (KT); \
    unsigned char* sd  = sMem + (size_t)((_kt) & 1) * 65536; \
    unsigned char* sdn = sMem + (size_t)(((_kt) & 1) ^ 1) * 65536; \
    /* P0: (qm,qn)=(0,0) */ \
    DSA(0); DSB(0); \
    if (STB) stageB(0, _kt + 1, sdn); \
    BARRIER(); LGKM0(); \
    __builtin_amdgcn_s_setprio(1); PHASE_MFMA(0, 0); __builtin_amdgcn_s_setprio(0); \
    VMC_P0; \
    BARRIER(); \
    /* P1: (0,1) */ \
    DSB(1); \
    if (STB) stageB(1, _kt + 1, sdn); \
    BARRIER(); LGKM0(); \
    __builtin_amdgcn_s_setprio(1); PHASE_MFMA(0, 1); __builtin_amdgcn_s_setprio(0); \
    BARRIER(); \
    /* P2: (1,1) */ \
    DSA(1); \
    if (STA) stageA(0, _kt + 2, sd); \
    BARRIER(); LGKM0(); \
    __builtin_amdgcn_s_setprio(1); PHASE_MFMA(1, 1); __builtin_amdgcn_s_setprio(0); \
    BARRIER(); \
    /* P3: (1,0) — no new ds_reads */ \
    if (STA) stageA(1, _kt + 2, sd); \
    BARRIER(); \
    __builtin_amdgcn_s_setprio(1); PHASE_MFMA(1, 0); __builtin_amdgcn_s_setprio(0); \
    VMC_P3; \
    BARRIER(); \
  } while (0)

#define EPILOG(QM) do { \
    _Pragma("unroll") \
    for (int i = 0; i < 4; ++i) { \
      _Pragma("unroll") \
      for (int t = 0; t < 4; ++t) { \
        const int rloc = (QM)*128 + wm*64 + i*16 + q*4 + t; \
        const int trg  = sTgt[rloc]; \
        float s = 0.0f; \
        _Pragma("unroll") \
        for (int j = 0; j < 2; ++j) { \
          { const int col = col0 + 0*128 + wn*32 + j*16 + m15; \
            const float v = acc##QM##0[i][j][t]; \
            if (col < VOCAB) s += __expf(v); \
            if (col == trg) TGT[row0 + rloc] = v; } \
          { const int col = col0 + 1*128 + wn*32 + j*16 + m15; \
            const float v = acc##QM##1[i][j][t]; \
            if (col < VOCAB) s += __expf(v); \
            if (col == trg) TGT[row0 + rloc] = v; } \
        } \
        _Pragma("unroll") \
        for (int o = 1; o < 16; o <<= 1) s += __shfl_xor(s, o, 64); \
        if (m15 == 0) atomicAdd(&S[row0 + rloc], s); \
      } } } while (0)

__global__ void __launch_bounds__(512, 2) cce_gemm_kernel(
    const unsigned short* __restrict__ ebf,
    const unsigned short* __restrict__ cbf,
    const int* __restrict__ targets,
    float* __restrict__ S,
    float* __restrict__ TGT) {
  __shared__ __align__(16) unsigned char sMem[2 * 65536];   // 128 KB
  __shared__ int sTgt[BM];

  const int bx   = blockIdx.x;
  const int rt   = bx & (N_RT - 1);
  const int vt   = bx >> 5;
  const int row0 = rt * BM;
  const int col0 = vt * BN;

  const int tid  = threadIdx.x;
  const int wid  = tid >> 6;
  const int lane = tid & 63;
  const int wm   = wid >> 2;     // 0..1
  const int wn   = wid & 3;      // 0..3
  const int m15  = lane & 15;
  const int q    = lane >> 4;    // 0..3

  if (tid < BM) sTgt[tid] = targets[row0 + tid];

  // staging: wave wid stages 2x16B per half-tile; row = wid*16 + l*8 + lane/8,
  // global chunk = (lane&7) ^ (lane>>3)  (inverse swizzle, row&7 == lane>>3)
  const int srow = wid * 16 + (lane >> 3);
  const int scol = ((lane & 7) ^ (lane >> 3)) * 8;
  const unsigned short* gA00 = ebf + (size_t)(row0 +   0 + srow + 0) * DMODEL + scol;
  const unsigned short* gA01 = ebf + (size_t)(row0 +   0 + srow + 8) * DMODEL + scol;
  const unsigned short* gA10 = ebf + (size_t)(row0 + 128 + srow + 0) * DMODEL + scol;
  const unsigned short* gA11 = ebf + (size_t)(row0 + 128 + srow + 8) * DMODEL + scol;
  const unsigned short* gB00 = cbf + (size_t)(col0 +   0 + srow + 0) * DMODEL + scol;
  const unsigned short* gB01 = cbf + (size_t)(col0 +   0 + srow + 8) * DMODEL + scol;
  const unsigned short* gB10 = cbf + (size_t)(col0 + 128 + srow + 0) * DMODEL + scol;
  const unsigned short* gB11 = cbf + (size_t)(col0 + 128 + srow + 8) * DMODEL + scol;

  // ds_read offsets: row*128 + (chunk ^ (row&7))*16 ; row&7 == m15&7
  const int aoff = (wm * 64 + m15) * 128;
  const int boff = (wn * 32 + m15) * 128;
  const int cks0 = ((0 + q) ^ (m15 & 7)) * 16;   // kstep 0
  const int cks1 = ((4 + q) ^ (m15 & 7)) * 16;   // kstep 1

  short8 a[4][2];                 // current A quadrant [i][kstep]
  short8 b0[2][2], b1[2][2];      // both B quadrants  [j][kstep]
  float4v acc00[4][2], acc01[4][2], acc10[4][2], acc11[4][2];
#pragma unroll
  for (int i = 0; i < 4; ++i)
#pragma unroll
    for (int j = 0; j < 2; ++j) {
      acc00[i][j] = (float4v)0.0f; acc01[i][j] = (float4v)0.0f;
      acc10[i][j] = (float4v)0.0f; acc11[i][j] = (float4v)0.0f;
    }

  // ---- prologue: queue order A0(0) A1(0) B0(0) B1(0) A0(1) A1(1) ----
  {
    unsigned char* buf0 = sMem;
    unsigned char* buf1 = sMem + 65536;
    stageA(0, 0, buf0);
    stageA(1, 0, buf0);
    stageB(0, 0, buf0);
    stageB(1, 0, buf0);
    stageA(0, 1, buf1);
    stageA(1, 1, buf1);
    asm volatile("s_waitcnt vmcnt(6) lgkmcnt(0)" ::: "memory");
    __builtin_amdgcn_s_barrier();
    asm volatile("" ::: "memory");
  }

  // ---- main loop: tiles 0 .. NKT-3 steady, last two peeled ----
  for (int kt = 0; kt < NKT - 2; ++kt) {
    KTILE(kt, 1, 1, VMCNT(6), VMCNT(6));
  }
  KTILE(NKT - 2, 1, 0, VMCNT(6), VMCNT(2));
  KTILE(NKT - 1, 0, 0, VMCNT(0), (void)0);

  // ---- fused epilogue: per-row sum(exp) + target-logit pick ----
  // C/D layout: col = m15, row = q*4 + t
  EPILOG(0);
  EPILOG(1);
}

// ---- finalize -----------------------------------------------------------

__global__ void finalize_kernel(const float* __restrict__ S,
                                const float* __restrict__ TGT,
                                const int* __restrict__ targets,
                                float* __restrict__ out) {
  __shared__ float rs[256];
  __shared__ int   rc[256];
  const int tid = threadIdx.x;
  float acc = 0.0f;
  int cnt = 0;
  for (int r = tid; r < N_TOK; r += 256) {
    const int t = targets[r];
    if (t != IGNORE_INDEX) {
      acc += logf(S[r]) - TGT[r];
      cnt++;
    }
  }
  rs[tid] = acc; rc[tid] = cnt;
  __syncthreads();
  for (int o = 128; o > 0; o >>= 1) {
    if (tid < o) { rs[tid] += rs[tid + o]; rc[tid] += rc[tid + o]; }
    __syncthreads();
  }
  if (tid == 0) out[0] = rs[0] / (float)(rc[0] > 0 ? rc[0] : 1);
}

// ---- launch -------------------------------------------------------------

extern "C" void kernel_launch(void* const* d_in, const int* in_sizes, int n_in,
                              void* d_out, int out_size, void* d_ws, size_t ws_size,
                              hipStream_t stream) {
  const float* e       = (const float*)d_in[0];
  const float* c       = (const float*)d_in[1];
  const int*   targets = (const int*)d_in[2];
  float* out = (float*)d_out;

  char* ws = (char*)d_ws;
  unsigned short* cbf = (unsigned short*)ws;                                   // VPAD*D bf16
  unsigned short* ebf = (unsigned short*)(ws + (size_t)VPAD * DMODEL * 2);     // N_TOK*D bf16
  float* S   = (float*)(ws + (size_t)VPAD * DMODEL * 2 + (size_t)N_TOK * DMODEL * 2);
  float* TGT = S + N_TOK;

  convert_c_kernel<<<dim3((unsigned)((size_t)VPAD * DMODEL / 4 / 256)), dim3(256), 0, stream>>>(c, cbf);
  convert_e_kernel<<<dim3((unsigned)((size_t)N_TOK * DMODEL / 4 / 256)), dim3(256), 0, stream>>>(e, ebf);
  init_kernel<<<dim3((2 * N_TOK + 255) / 256), dim3(256), 0, stream>>>(S);

  cce_gemm_kernel<<<dim3(N_RT * N_VT), dim3(512), 0, stream>>>(ebf, cbf, targets, S, TGT);

  finalize_kernel<<<dim3(1), dim3(256), 0, stream>>>(S, TGT, targets, out);
}